// Round 8
// baseline (272.591 us; speedup 1.0000x reference)
//
#include <hip/hip_runtime.h>

// ---- problem constants ----
#define B_   64
#define L_   256
#define E_   1600
#define P_   100
#define KP   4
// output layout (flat float32 concat, reference return order)
#define N0 34
#define N1 33
#define N2 33
#define LOUT0 253
#define LOUT1 250
#define LOUT2 247
#define OFF_PD 0
#define OFF_D0 6400
#define OFF_D1 (OFF_D0 + B_*N0*LOUT0)   // 556928
#define OFF_D2 (OFF_D1 + B_*N1*LOUT1)   // 1084928
#define OFF_CO (OFF_D2 + B_*N2*LOUT2)   // 1606592

// ---- ws layout (fast path): frag-ordered B^T bf16 + p2 ----
// B stored as [25 row-tiles][25 c][2 ks][64 lanes][16B] so a wave's B-frag is
// one coalesced 16B/lane load: chunk = (nrt*25 + c)*2 + ks, addr = chunk*1024
// + lane*16, lane = jq*16 + mrow holds B[nrt*16+mrow][c*64+ks*32+jq*8 ..+8].
#define WS_BT   0ull                          // bf16, 1.28 MB
#define WS_P2   1310720ull                    // f32 [128]
#define WS_NEED (WS_P2 + 512ull)

typedef float f32x4 __attribute__((ext_vector_type(4)));
typedef float f32x8 __attribute__((ext_vector_type(8)));
typedef unsigned short ushort8v __attribute__((ext_vector_type(8)));
typedef __bf16 bf16x8 __attribute__((ext_vector_type(8)));
typedef _Float16 f16;

__device__ __forceinline__ unsigned short bf16rne(float f) {
    unsigned u = __float_as_uint(f);
    u += 0x7FFFu + ((u >> 16) & 1u);
    return (unsigned short)(u >> 16);
}

// ===========================================================================
// FAST PATH
// ===========================================================================

// prep: proto fp32 -> frag-ordered B^T bf16 (+ p2); init proto_dist to +INF
__global__ __launch_bounds__(256) void proto_prepB_perm(
        const float* __restrict__ proto, char* __restrict__ ws,
        float* __restrict__ out) {
    int q = blockIdx.x;
    int wave = threadIdx.x >> 6, lane = threadIdx.x & 63;
    if (q < 25) {                        // one wave per proto
        int p = q * 4 + wave;            // [0,100)
        const float4* r = (const float4*)(proto + (size_t)p * (E_ * KP));
        unsigned short* bt = (unsigned short*)(ws + WS_BT);
        int nrt = p >> 2;                // B row-tile = p/4
        int mr0 = (p & 3) * 4;           // mrow of tap 0: row n=4p+t -> n%16
        float acc = 0.f;
        #pragma unroll
        for (int it = 0; it < 25; ++it) {
            int e = it * 64 + lane;
            float4 v = r[e];             // taps 0..3 of proto[p][e]
            acc += v.x*v.x + v.y*v.y + v.z*v.z + v.w*v.w;
            int c  = e >> 6;
            int ks = (e >> 5) & 1;
            int jq = (e >> 3) & 3;
            int j  = e & 7;
            unsigned base = ((unsigned)((nrt * 25 + c) * 2 + ks) << 9)
                          + (unsigned)((jq * 16 + mr0) * 8 + j);
            bt[base]      = bf16rne(v.x);
            bt[base + 8]  = bf16rne(v.y);
            bt[base + 16] = bf16rne(v.z);
            bt[base + 24] = bf16rne(v.w);
        }
        #pragma unroll
        for (int off = 32; off; off >>= 1) acc += __shfl_down(acc, off);
        if (lane == 0) ((float*)(ws + WS_P2))[p] = acc;
    } else {                             // init proto_dist to +INF
        for (int i = threadIdx.x; i < B_ * P_; i += 256)
            out[OFF_PD + i] = __uint_as_float(0x7F800000u);
    }
}

// main: barrier-free K-loop. A frags register-direct from fp32 emb (L3-hot)
// with packed bf16 convert + fused s; B frags register-direct from
// frag-ordered bf16 ws. LDS used only by the dist epilogue.
__global__ __launch_bounds__(192, 2) void proto_main_direct(
        const float* __restrict__ emb, const char* __restrict__ ws,
        float* __restrict__ out) {

    __shared__ __align__(16) char smem[24064];

    // XCD grouping: all 10 blocks of one b on the same XCD (bx&7 heuristic)
    int bx    = blockIdx.x;              // 0..639
    int lb    = (bx & 7) * 80 + (bx >> 3);
    int b     = lb / 10;
    int inner = lb % 10;
    int m     = inner / 5;
    int n_blk = inner % 5;
    int r0    = m ? 112 : 0;
    int pbase = n_blk * 20;

    int tid  = threadIdx.x;
    int lane = tid & 63;
    int wave = tid >> 6;         // 0..2, wave-tile 48x80
    int mrow = lane & 15;
    int jq   = lane >> 4;        // 0..3

    // A: per-frag row pointers (lane reads its own row, 32B per K-32)
    const float* Aptr[3];
    #pragma unroll
    for (int mi = 0; mi < 3; ++mi) {
        int row = b * L_ + r0 + wave * 48 + mi * 16 + mrow;
        Aptr[mi] = emb + (size_t)row * E_ + jq * 8;
    }
    // B: per-ni chunk base (fully coalesced: base + lane*16)
    const char* Bptr[5];
    #pragma unroll
    for (int ni = 0; ni < 5; ++ni) {
        int nrt = n_blk * 5 + ni;
        Bptr[ni] = ws + WS_BT + (size_t)(nrt * 50) * 1024 + lane * 16;
    }

    f32x4 acc[3][5] = {};
    float sacc[3] = {0.f, 0.f, 0.f};

    for (int c = 0; c < 25; ++c) {
        #pragma unroll
        for (int ks = 0; ks < 2; ++ks) {
            int k0   = c * 64 + ks * 32;
            int boff = (c * 2 + ks) * 1024;
            f32x4 f0[3], f1[3];
            ushort8v bfv[5];
            #pragma unroll
            for (int mi = 0; mi < 3; ++mi) {
                f0[mi] = *(const f32x4*)(Aptr[mi] + k0);
                f1[mi] = *(const f32x4*)(Aptr[mi] + k0 + 4);
            }
            #pragma unroll
            for (int ni = 0; ni < 5; ++ni)
                bfv[ni] = *(const ushort8v*)(Bptr[ni] + boff);
            ushort8v af[3];
            #pragma unroll
            for (int mi = 0; mi < 3; ++mi) {
                sacc[mi] += f0[mi][0]*f0[mi][0] + f0[mi][1]*f0[mi][1]
                          + f0[mi][2]*f0[mi][2] + f0[mi][3]*f0[mi][3]
                          + f1[mi][0]*f1[mi][0] + f1[mi][1]*f1[mi][1]
                          + f1[mi][2]*f1[mi][2] + f1[mi][3]*f1[mi][3];
                f32x8 fv;
                fv[0]=f0[mi][0]; fv[1]=f0[mi][1]; fv[2]=f0[mi][2]; fv[3]=f0[mi][3];
                fv[4]=f1[mi][0]; fv[5]=f1[mi][1]; fv[6]=f1[mi][2]; fv[7]=f1[mi][3];
                af[mi] = __builtin_bit_cast(ushort8v,
                            __builtin_convertvector(fv, bf16x8));
            }
            #pragma unroll
            for (int mi = 0; mi < 3; ++mi)
                #pragma unroll
                for (int ni = 0; ni < 5; ++ni)
                    acc[mi][ni] = __builtin_amdgcn_mfma_f32_16x16x32_bf16(
                        __builtin_bit_cast(bf16x8, af[mi]),
                        __builtin_bit_cast(bf16x8, bfv[ni]),
                        acc[mi][ni], 0, 0, 0);
        }
    }

    // ---- epilogue: Y (fp16) + fused s -> LDS, form distances ----
    f16*      Yh     = (f16*)smem;                      // [144][81] = 23328 B
    float*    slds   = (float*)(smem + 23328);          // [144]
    float*    p2lds  = (float*)(smem + 23904);          // [20]
    unsigned* minlds = (unsigned*)(smem + 23984);       // [20]

    {
        int colq = lane & 15;
        int rowq = (lane >> 4) * 4;
        #pragma unroll
        for (int mi = 0; mi < 3; ++mi) {
            int row = wave * 48 + mi * 16 + rowq;
            #pragma unroll
            for (int ni = 0; ni < 5; ++ni) {
                int col = ni * 16 + colq;
                #pragma unroll
                for (int r = 0; r < 4; ++r)
                    Yh[(row + r) * 81 + col] = (f16)acc[mi][ni][r];
            }
        }
    }
    // s: reduce sacc over the 4 jq lane-groups (xor 16, 32), jq==0 writes
    #pragma unroll
    for (int mi = 0; mi < 3; ++mi) {
        float v = sacc[mi];
        v += __shfl_xor(v, 16);
        v += __shfl_xor(v, 32);
        sacc[mi] = v;
    }
    if (jq == 0) {
        #pragma unroll
        for (int mi = 0; mi < 3; ++mi)
            slds[wave * 48 + mi * 16 + mrow] = sacc[mi];
    }
    if (tid < 20) {
        p2lds[tid] = ((const float*)(ws + WS_P2))[pbase + tid];
        minlds[tid] = 0x7F800000u;
    }
    __syncthreads();

    int l_lo = m * 128;
    for (int idx = tid; idx < 20 * 128; idx += 192) {
        int pl  = idx >> 7;
        int lof = idx & 127;
        int p = pbase + pl;
        int d, Lout, nseg, pseg; size_t segbase;
        if (p < 34)      { d = 1; Lout = LOUT0; segbase = OFF_D0; pseg = p;      nseg = N0; }
        else if (p < 67) { d = 2; Lout = LOUT1; segbase = OFF_D1; pseg = p - 34; nseg = N1; }
        else             { d = 3; Lout = LOUT2; segbase = OFF_D2; pseg = p - 67; nseg = N2; }
        int l = l_lo + lof;
        if (l < Lout) {
            int rl = l - r0;
            int c0 = pl * 4;
            float xp = (float)Yh[rl * 81 + c0]
                     + (float)Yh[(rl + d) * 81 + c0 + 1]
                     + (float)Yh[(rl + 2*d) * 81 + c0 + 2]
                     + (float)Yh[(rl + 3*d) * 81 + c0 + 3];
            float x2 = slds[rl] + slds[rl + d] + slds[rl + 2*d] + slds[rl + 3*d];
            float dist = sqrtf(fabsf(x2 - 2.f * xp + p2lds[pl]));
            out[segbase + ((size_t)b * nseg + pseg) * Lout + l] = dist;
            atomicMin(&minlds[pl], __float_as_uint(dist));
        }
    }
    __syncthreads();
    if (tid < 20)
        atomicMin((unsigned*)out + OFF_PD + b * P_ + pbase + tid, minlds[tid]);
}

// ===========================================================================
// FALLBACK PATH (round-1 kernels, used only if ws too small)
// ===========================================================================
#define TM   144
#define ASTR 40
#define YSTR 81

__global__ __launch_bounds__(256) void proto_prep_kernel(
        const float* __restrict__ emb, const float* __restrict__ proto,
        float* __restrict__ ws_s, float* __restrict__ ws_p2,
        float* __restrict__ out) {
    int q = blockIdx.x;
    int wave = threadIdx.x >> 6, lane = threadIdx.x & 63;
    if (q < 4096) {
        int row = q * 4 + wave;
        const float4* r = (const float4*)(emb + (size_t)row * E_);
        float acc = 0.f;
        #pragma unroll
        for (int it = 0; it < 7; ++it) {
            int e4 = it * 64 + lane;
            if (e4 < 400) {
                float4 v = r[e4];
                acc += v.x*v.x + v.y*v.y + v.z*v.z + v.w*v.w;
            }
        }
        #pragma unroll
        for (int off = 32; off; off >>= 1) acc += __shfl_down(acc, off);
        if (lane == 0) ws_s[row] = acc;
    } else if (q < 4121) {
        int p = (q - 4096) * 4 + wave;
        if (p < P_) {
            const float4* r = (const float4*)(proto + (size_t)p * (E_ * KP));
            float acc = 0.f;
            #pragma unroll
            for (int it = 0; it < 25; ++it) {
                float4 v = r[it * 64 + lane];
                acc += v.x*v.x + v.y*v.y + v.z*v.z + v.w*v.w;
            }
            #pragma unroll
            for (int off = 32; off; off >>= 1) acc += __shfl_down(acc, off);
            if (lane == 0) ws_p2[p] = acc;
        }
    } else {
        for (int i = threadIdx.x; i < B_ * P_; i += 256)
            out[OFF_PD + i] = __uint_as_float(0x7F800000u);
    }
}

__global__ __launch_bounds__(192) void proto_main_kernel(
        const float* __restrict__ emb, const float* __restrict__ proto,
        const float* __restrict__ ws_s, const float* __restrict__ ws_p2,
        float* __restrict__ out) {

    __shared__ __align__(16) char smem[47392];
    unsigned short* Ald = (unsigned short*)smem;
    unsigned short* Bld = (unsigned short*)(smem + TM*ASTR*2);

    int bx = blockIdx.x;
    int n_blk = bx % 5;
    int m     = (bx / 5) & 1;
    int b     = bx / 10;
    int r0    = m ? 112 : 0;
    int pbase = n_blk * 20;

    const float* Abase = emb + ((size_t)(b * L_ + r0)) * E_;
    const float* Bbase = proto + (size_t)pbase * (E_ * KP);

    int tid  = threadIdx.x;
    int lane = tid & 63;
    int wave = tid >> 6;
    int mrow = lane & 15;
    int kq   = (lane >> 4) * 8;

    f32x4 acc[3][5] = {};

    for (int c = 0; c < E_ / 32; ++c) {
        int e0 = c * 32;
        #pragma unroll
        for (int i = 0; i < 6; ++i) {
            int idx = tid + i * 192;
            int row = idx >> 3;
            int e4  = idx & 7;
            float4 v = *(const float4*)(Abase + (size_t)row * E_ + e0 + e4 * 4);
            ushort4 bv = make_ushort4(bf16rne(v.x), bf16rne(v.y),
                                      bf16rne(v.z), bf16rne(v.w));
            *(ushort4*)&Ald[row * ASTR + e4 * 4] = bv;
        }
        for (int idx = tid; idx < 640; idx += 192) {
            int pl = idx >> 5;
            int el = idx & 31;
            float4 v = *(const float4*)(Bbase + (size_t)pl * (E_ * KP)
                                        + (size_t)(e0 + el) * KP);
            Bld[(4*pl + 0) * ASTR + el] = bf16rne(v.x);
            Bld[(4*pl + 1) * ASTR + el] = bf16rne(v.y);
            Bld[(4*pl + 2) * ASTR + el] = bf16rne(v.z);
            Bld[(4*pl + 3) * ASTR + el] = bf16rne(v.w);
        }
        __syncthreads();

        ushort8v af[3], bfr[5];
        #pragma unroll
        for (int mi = 0; mi < 3; ++mi)
            af[mi] = *(const ushort8v*)&Ald[(wave*48 + mi*16 + mrow) * ASTR + kq];
        #pragma unroll
        for (int ni = 0; ni < 5; ++ni)
            bfr[ni] = *(const ushort8v*)&Bld[(ni*16 + mrow) * ASTR + kq];
        #pragma unroll
        for (int mi = 0; mi < 3; ++mi)
            #pragma unroll
            for (int ni = 0; ni < 5; ++ni)
                acc[mi][ni] = __builtin_amdgcn_mfma_f32_16x16x32_bf16(
                    __builtin_bit_cast(bf16x8, af[mi]),
                    __builtin_bit_cast(bf16x8, bfr[ni]),
                    acc[mi][ni], 0, 0, 0);
        __syncthreads();
    }

    float*    Ylds   = (float*)smem;
    float*    slds   = (float*)(smem + TM * YSTR * 4);
    float*    p2lds  = slds + TM;
    unsigned* minlds = (unsigned*)(p2lds + 20);

    {
        int colq = lane & 15;
        int rowq = (lane >> 4) * 4;
        #pragma unroll
        for (int mi = 0; mi < 3; ++mi) {
            int row = wave * 48 + mi * 16 + rowq;
            #pragma unroll
            for (int ni = 0; ni < 5; ++ni) {
                int col = ni * 16 + colq;
                #pragma unroll
                for (int r = 0; r < 4; ++r)
                    Ylds[(row + r) * YSTR + col] = acc[mi][ni][r];
            }
        }
    }
    if (tid < TM) slds[tid] = ws_s[b * L_ + r0 + tid];
    if (tid < 20) { p2lds[tid] = ws_p2[pbase + tid]; minlds[tid] = 0x7F800000u; }
    __syncthreads();

    int l_lo = m * 128;
    for (int idx = tid; idx < 20 * 128; idx += 192) {
        int pl  = idx >> 7;
        int lof = idx & 127;
        int p = pbase + pl;
        int d, Lout, nseg, pseg; size_t segbase;
        if (p < 34)      { d = 1; Lout = LOUT0; segbase = OFF_D0; pseg = p;      nseg = N0; }
        else if (p < 67) { d = 2; Lout = LOUT1; segbase = OFF_D1; pseg = p - 34; nseg = N1; }
        else             { d = 3; Lout = LOUT2; segbase = OFF_D2; pseg = p - 67; nseg = N2; }
        int l = l_lo + lof;
        if (l < Lout) {
            int rl = l - r0;
            int c0 = pl * 4;
            float xp = Ylds[rl * YSTR + c0]
                     + Ylds[(rl + d) * YSTR + c0 + 1]
                     + Ylds[(rl + 2*d) * YSTR + c0 + 2]
                     + Ylds[(rl + 3*d) * YSTR + c0 + 3];
            float x2 = slds[rl] + slds[rl + d] + slds[rl + 2*d] + slds[rl + 3*d];
            float dist = sqrtf(fabsf(x2 - 2.f * xp + p2lds[pl]));
            out[segbase + ((size_t)b * nseg + pseg) * Lout + l] = dist;
            atomicMin(&minlds[pl], __float_as_uint(dist));
        }
    }
    __syncthreads();
    if (tid < 20)
        atomicMin((unsigned*)out + OFF_PD + b * P_ + pbase + tid, minlds[tid]);
}

// ---------------------------------------------------------------------------
// fc: class_out[b,c] = sum_p proto_dist[b,p] * fc_w[c,p]
// ---------------------------------------------------------------------------
__global__ __launch_bounds__(128) void proto_fc_kernel(
        const float* __restrict__ fc_w, float* __restrict__ out) {
    int t = threadIdx.x;      // 128 = 64 b * 2 c
    int b = t >> 1, c = t & 1;
    const float* pd = out + OFF_PD + b * P_;
    const float* w  = fc_w + c * P_;
    float s = 0.f;
    #pragma unroll 4
    for (int p = 0; p < P_; ++p) s += pd[p] * w[p];
    out[OFF_CO + b * 2 + c] = s;
}

extern "C" void kernel_launch(void* const* d_in, const int* in_sizes, int n_in,
                              void* d_out, int out_size, void* d_ws, size_t ws_size,
                              hipStream_t stream) {
    const float* emb   = (const float*)d_in[0];   // [64,256,1600]
    const float* proto = (const float*)d_in[1];   // [100,1600,4]
    const float* fc_w  = (const float*)d_in[2];   // [2,100]
    float* out  = (float*)d_out;

    if (ws_size >= WS_NEED) {
        char* ws = (char*)d_ws;
        proto_prepB_perm<<<26, 256, 0, stream>>>(proto, ws, out);
        proto_main_direct<<<640, 192, 0, stream>>>(emb, ws, out);
    } else {
        float* ws_s  = (float*)d_ws;              // 16384 floats
        float* ws_p2 = ws_s + B_ * L_;            // 100 floats
        proto_prep_kernel<<<4122, 256, 0, stream>>>(emb, proto, ws_s, ws_p2, out);
        proto_main_kernel<<<640, 192, 0, stream>>>(emb, proto, ws_s, ws_p2, out);
    }
    proto_fc_kernel<<<1, 128, 0, stream>>>(fc_w, out);
}